// Round 1
// baseline (67.541 us; speedup 1.0000x reference)
//
#include <hip/hip_runtime.h>

// L0ConjunctionLayer, single fused kernel (no workspace, one launch):
//   out[b,o] = prod_k (1 - t),  t = y[b,k]*w[k,o],  y = 1 - x*z, z = gate(qz)
//   log(1-t) = -(t + t^2/2 + t^3/3 + O(t^4)),  t <= 0.1 (w <= 0.1)
//   => out = exp(-(S1 + S2/2 + S3/3)),  Sp = matmul(Y^p, W^p)  [elementwise powers]
//
// Previous structure (prep kernel -> Yf/Wf in workspace -> main kernel) spent
// its time on launch/serialization overhead and the 256 MB workspace poison
// fill (rocprof top-5 = fillBufferAligned @ ~40.5 us), not on compute
// (~1.6 GFLOP = 0.65 us at MFMA rate). This version:
//   - ONE kernel, ZERO workspace use.
//   - Per block (4 waves, tile 64x16 of C): compute z-gate into LDS, build
//     W fragments AND their fp16 powers (b, b^2, b^3) into 48 KB LDS once
//     (shared by the 4 waves; replaces per-iter b-power pk_muls with
//     ds_read_b128).
//   - Per wave, K-loop 16 iters: build A frag from x directly (2x float4,
//     same fp32 fmaf + cvt math as old prep => identical numerics), square/
//     cube in-register, 3 MFMA. x re-read 16x across blocks but L2/L3-hot
//     (x = 4 MB).
// Fragment layouts (m120/m89): A[m=lane&15][k=(lane>>4)*8+j],
//   B[k=(lane>>4)*8+j][n=lane&15], C col=lane&15, row=(lane>>4)*4+i.

typedef _Float16 v8h __attribute__((ext_vector_type(8)));
typedef float v4f __attribute__((ext_vector_type(4)));

#define DIM_B 2048
#define DIM_I 512
#define DIM_O 256

__global__ __launch_bounds__(256, 2) void l0conj_fused(
    const float* __restrict__ x,    // [2048][512]
    const float* __restrict__ w,    // [512][256]
    const float* __restrict__ qz,   // [512]
    float* __restrict__ out)        // [2048][256]
{
    const int t = threadIdx.x;
    const int lane = t & 63;
    const int wid = t >> 6;
    const int m16 = blockIdx.x * 4 + wid;   // 0..127
    const int n16 = blockIdx.y;             // 0..15

    __shared__ float zS[DIM_I];              // 2 KB
    __shared__ _Float16 Bf[3][16][64][8];    // 48 KB: b, b^2, b^3 fragments

    // ---- z gate (identical math to old prep) ----
    for (int i = t; i < DIM_I; i += 256) {
        float q = qz[i];
        float sig = 1.0f / (1.0f + __expf(-q));
        float z = fmaf(sig, 1.2f, -0.1f);
        zS[i] = fminf(fmaxf(z, 0.0f), 1.0f);
    }

    // ---- W fragments + powers into LDS: wave handles kk = wid*4 .. +3 ----
    {
        const int c = lane & 15, q = lane >> 4;
#pragma unroll
        for (int i = 0; i < 4; ++i) {
            const int kk = wid * 4 + i;
            const float* wp = w + (size_t)(kk * 32 + q * 8) * DIM_O + n16 * 16 + c;
            v8h b;
#pragma unroll
            for (int j = 0; j < 8; ++j) b[j] = (_Float16)wp[(size_t)j * DIM_O];
            const v8h b2 = b * b;        // v_pk_mul_f16, same as old main
            const v8h b3 = b2 * b;
            *(v8h*)&Bf[0][kk][lane][0] = b;
            *(v8h*)&Bf[1][kk][lane][0] = b2;
            *(v8h*)&Bf[2][kk][lane][0] = b3;
        }
    }
    __syncthreads();

    // ---- K-loop: A frag from x on the fly, 3 MFMA / iter ----
    const int r = lane & 15, q = lane >> 4;
    const float* xp = x + (size_t)(m16 * 16 + r) * DIM_I + q * 8;
    const float* zp0 = zS + q * 8;

    v4f s1 = {0.f, 0.f, 0.f, 0.f};
    v4f s2 = {0.f, 0.f, 0.f, 0.f};
    v4f s3 = {0.f, 0.f, 0.f, 0.f};

    float4 x0 = *(const float4*)(xp);
    float4 x1 = *(const float4*)(xp + 4);

#pragma unroll
    for (int k = 0; k < 16; ++k) {
        float4 nx0, nx1;
        if (k < 15) {  // prefetch next x while MFMAs run
            nx0 = *(const float4*)(xp + (k + 1) * 32);
            nx1 = *(const float4*)(xp + (k + 1) * 32 + 4);
        }
        const float4 z0 = *(const float4*)(zp0 + k * 32);      // LDS broadcast
        const float4 z1 = *(const float4*)(zp0 + k * 32 + 4);
        v8h a;
        a[0] = (_Float16)fmaf(-x0.x, z0.x, 1.0f);
        a[1] = (_Float16)fmaf(-x0.y, z0.y, 1.0f);
        a[2] = (_Float16)fmaf(-x0.z, z0.z, 1.0f);
        a[3] = (_Float16)fmaf(-x0.w, z0.w, 1.0f);
        a[4] = (_Float16)fmaf(-x1.x, z1.x, 1.0f);
        a[5] = (_Float16)fmaf(-x1.y, z1.y, 1.0f);
        a[6] = (_Float16)fmaf(-x1.z, z1.z, 1.0f);
        a[7] = (_Float16)fmaf(-x1.w, z1.w, 1.0f);
        const v8h a2 = a * a;
        const v8h a3 = a2 * a;
        const v8h b  = *(const v8h*)&Bf[0][k][lane][0];
        const v8h b2 = *(const v8h*)&Bf[1][k][lane][0];
        const v8h b3 = *(const v8h*)&Bf[2][k][lane][0];
        s1 = __builtin_amdgcn_mfma_f32_16x16x32_f16(a,  b,  s1, 0, 0, 0);
        s2 = __builtin_amdgcn_mfma_f32_16x16x32_f16(a2, b2, s2, 0, 0, 0);
        s3 = __builtin_amdgcn_mfma_f32_16x16x32_f16(a3, b3, s3, 0, 0, 0);
        x0 = nx0;
        x1 = nx1;
    }

    // ---- Epilogue: C/D layout col=lane&15, row=(lane>>4)*4+i ----
    const int col = lane & 15;
    const int row4 = (lane >> 4) * 4;
    float* op = out + (size_t)(m16 * 16 + row4) * DIM_O + n16 * 16 + col;
#pragma unroll
    for (int i = 0; i < 4; ++i) {
        const float S = s1[i] + 0.5f * s2[i] + (1.0f / 3.0f) * s3[i];
        op[(size_t)i * DIM_O] = __expf(-S);
    }
}

extern "C" void kernel_launch(void* const* d_in, const int* in_sizes, int n_in,
                              void* d_out, int out_size, void* d_ws, size_t ws_size,
                              hipStream_t stream) {
    const float* x = (const float*)d_in[0];   // [2048, 512]
    const float* w = (const float*)d_in[1];   // [512, 256]
    const float* qz = (const float*)d_in[2];  // [512]
    float* out = (float*)d_out;               // [2048, 256]
    (void)d_ws; (void)ws_size;                // workspace intentionally unused

    l0conj_fused<<<dim3(32, 16), dim3(256), 0, stream>>>(x, w, qz, out);
}

// Round 2
// 66.412 us; speedup vs baseline: 1.0170x; 1.0170x over previous
//
#include <hip/hip_runtime.h>

// L0ConjunctionLayer, single fused kernel, latency-tolerant restructure:
//   out[b,o] = prod_k (1 - t),  t = y[b,k]*w[k,o],  y = 1 - x*z, z = gate(qz)
//   log(1-t) = -(t + t^2/2 + t^3/3),  w <= 0.1  =>  out = exp(-(S1+S2/2+S3/3))
//
// R1 post-mortem: the 40.5 us workspace poison fill is a FIXED harness cost
// (present even with ws unused). Controllable budget = dur_us - 40.5.
// The R1 fused kernel (27 us) was LATENCY-bound: 2 waves/SIMD, 16-iter
// dependent K-loop, 1-deep prefetch vs 200-900 cyc load latency (poison
// evicts L2/L3 every iter), serial preamble before any MFMA.
//
// This version:
//   - K-split x2: 8 waves/block (512 thr), waves [0..3]=k 0..255,
//     [4..7]=k 256..511 -> 4096 waves = 4 waves/SIMD (2x latency hiding),
//     per-wave chain halves to 8 iters. fp32 cross-half reduce in LDS.
//   - Depth-2 x prefetch; first 2 iters' loads issued BEFORE the preamble
//     (overlap HBM latency with z-gate + W-build).
//   - B: only power-1 fragments in LDS (16 KB, built 2 k-tiles/wave);
//     b^2, b^3 in-register (8 pk_mul/iter). LDS total 30 KB.
//   - Per-term math identical to R1 (fp32 fmaf -> fp16 cvt, fp16 powers,
//     fp32 MFMA accum) -> absmax unchanged (~1.2e-10); only fp32 add order
//     changes (half-sums added once).
// Fragment layouts (m120/m89): A[m=lane&15][k=(lane>>4)*8+j],
//   B[k=(lane>>4)*8+j][n=lane&15], C col=lane&15, row=(lane>>4)*4+i.

typedef _Float16 v8h __attribute__((ext_vector_type(8)));
typedef float v4f __attribute__((ext_vector_type(4)));

#define DIM_B 2048
#define DIM_I 512
#define DIM_O 256

__global__ __launch_bounds__(512, 4) void l0conj_fused(
    const float* __restrict__ x,    // [2048][512]
    const float* __restrict__ w,    // [512][256]
    const float* __restrict__ qz,   // [512]
    float* __restrict__ out)        // [2048][256]
{
    const int t = threadIdx.x;
    const int lane = t & 63;
    const int wid = t >> 6;         // 0..7
    const int wm = wid & 3;         // which m-tile of the block
    const int half = wid >> 2;      // which K half
    const int m16 = blockIdx.x * 4 + wm;   // 0..127
    const int n16 = blockIdx.y;            // 0..15

    __shared__ float zS[DIM_I];             // 2 KB
    __shared__ _Float16 Bf[16][64][8];      // 16 KB: power-1 B fragments
    __shared__ v4f red[4][3][64];           // 12 KB: cross-half reduce

    const int r = lane & 15, q = lane >> 4;
    const float* xp = x + (size_t)(m16 * 16 + r) * DIM_I + half * 256 + q * 8;

    // ---- pre-issue iter0/iter1 x loads: HBM latency overlaps the preamble
    float4 x0 = *(const float4*)(xp);
    float4 x1 = *(const float4*)(xp + 4);
    float4 y0 = *(const float4*)(xp + 32);
    float4 y1 = *(const float4*)(xp + 36);

    // ---- z gate (identical math to R1; 512 threads = 1 element each)
    {
        float qv = qz[t];
        float sig = 1.0f / (1.0f + __expf(-qv));
        float z = fmaf(sig, 1.2f, -0.1f);
        zS[t] = fminf(fmaxf(z, 0.0f), 1.0f);
    }

    // ---- W power-1 fragments into LDS: 2 k-tiles per wave
    {
        const int c = lane & 15;
#pragma unroll
        for (int i2 = 0; i2 < 2; ++i2) {
            const int kk = wid * 2 + i2;   // 0..15
            const float* wp = w + (size_t)(kk * 32 + q * 8) * DIM_O + n16 * 16 + c;
            v8h b;
#pragma unroll
            for (int j = 0; j < 8; ++j) b[j] = (_Float16)wp[(size_t)j * DIM_O];
            *(v8h*)&Bf[kk][lane][0] = b;
        }
    }
    __syncthreads();

    // ---- K-loop: 8 iters per wave, depth-2 prefetch, 3 MFMA / iter
    const float* zp0 = zS + half * 256 + q * 8;

    v4f s1 = {0.f, 0.f, 0.f, 0.f};
    v4f s2 = {0.f, 0.f, 0.f, 0.f};
    v4f s3 = {0.f, 0.f, 0.f, 0.f};

#pragma unroll
    for (int k = 0; k < 8; ++k) {
        float4 n0, n1;
        if (k < 6) {   // depth-2 prefetch
            n0 = *(const float4*)(xp + (k + 2) * 32);
            n1 = *(const float4*)(xp + (k + 2) * 32 + 4);
        }
        const float4 z0 = *(const float4*)(zp0 + k * 32);   // LDS broadcast
        const float4 z1 = *(const float4*)(zp0 + k * 32 + 4);
        v8h a;
        a[0] = (_Float16)fmaf(-x0.x, z0.x, 1.0f);
        a[1] = (_Float16)fmaf(-x0.y, z0.y, 1.0f);
        a[2] = (_Float16)fmaf(-x0.z, z0.z, 1.0f);
        a[3] = (_Float16)fmaf(-x0.w, z0.w, 1.0f);
        a[4] = (_Float16)fmaf(-x1.x, z1.x, 1.0f);
        a[5] = (_Float16)fmaf(-x1.y, z1.y, 1.0f);
        a[6] = (_Float16)fmaf(-x1.z, z1.z, 1.0f);
        a[7] = (_Float16)fmaf(-x1.w, z1.w, 1.0f);
        const v8h a2 = a * a;                 // v_pk_mul_f16
        const v8h a3 = a2 * a;
        const v8h b  = *(const v8h*)&Bf[half * 8 + k][lane][0];
        const v8h b2 = b * b;
        const v8h b3 = b2 * b;
        s1 = __builtin_amdgcn_mfma_f32_16x16x32_f16(a,  b,  s1, 0, 0, 0);
        s2 = __builtin_amdgcn_mfma_f32_16x16x32_f16(a2, b2, s2, 0, 0, 0);
        s3 = __builtin_amdgcn_mfma_f32_16x16x32_f16(a3, b3, s3, 0, 0, 0);
        x0 = y0; x1 = y1; y0 = n0; y1 = n1;
    }

    // ---- cross-half reduce (fp32), then epilogue by half-0 waves
    if (half == 1) {
        red[wm][0][lane] = s1;
        red[wm][1][lane] = s2;
        red[wm][2][lane] = s3;
    }
    __syncthreads();
    if (half == 0) {
        s1 += red[wm][0][lane];
        s2 += red[wm][1][lane];
        s3 += red[wm][2][lane];
        const int col = lane & 15;
        const int row4 = (lane >> 4) * 4;
        float* op = out + (size_t)(m16 * 16 + row4) * DIM_O + n16 * 16 + col;
#pragma unroll
        for (int i = 0; i < 4; ++i) {
            const float S = s1[i] + 0.5f * s2[i] + (1.0f / 3.0f) * s3[i];
            op[(size_t)i * DIM_O] = __expf(-S);
        }
    }
}

extern "C" void kernel_launch(void* const* d_in, const int* in_sizes, int n_in,
                              void* d_out, int out_size, void* d_ws, size_t ws_size,
                              hipStream_t stream) {
    const float* x = (const float*)d_in[0];   // [2048, 512]
    const float* w = (const float*)d_in[1];   // [512, 256]
    const float* qz = (const float*)d_in[2];  // [512]
    float* out = (float*)d_out;               // [2048, 256]
    (void)d_ws; (void)ws_size;                // workspace intentionally unused

    l0conj_fused<<<dim3(32, 16), dim3(512), 0, stream>>>(x, w, qz, out);
}

// Round 3
// 63.616 us; speedup vs baseline: 1.0617x; 1.0440x over previous
//
#include <hip/hip_runtime.h>

// L0ConjunctionLayer, single fused kernel, v3 (n-fanout + K-split x4):
//   out[b,o] = prod_k (1 - t),  t = y[b,k]*w[k,o],  y = 1 - x*z, z = gate(qz)
//   log(1-t) = -(t + t^2/2 + t^3/3),  w <= 0.1  =>  out = exp(-(S1+S2/2+S3/3))
//
// R2 post-mortem: harness floor ~58-61 us (268 MB poison fill @40.3 us +
// ~29 tiny restore dispatches/iter). Fused-kernel deficit vs R0's prep+main
// attributed to A-operand traffic: fp32 x re-read 16x (64 MB, cold) vs
// R0's packed fp16 Yf (32 MB, L2-hot).
//
// v3 structure (grid (64,8) x 512 thr, 8 waves = 2 m-tiles x 4 K-quarters,
// block covers 1 n-pair):
//   - n-fanout 2: each wave computes 2 n16 tiles from ONE A fragment
//     -> x traffic halves to 32 MB (parity with Yf) with no prep kernel.
//   - K-split x4: per-wave chain = 4 iters; 4096 waves = 4 waves/SIMD.
//   - Entire per-wave x tile (4 iters x 32 B) pre-issued BEFORE the
//     preamble -> K-loop has zero exposed global latency (covered by
//     z-gate + W-build).
//   - 6 MFMA + 6 pk_mul per iter against 2 LDS b-reads. B power-1 frags
//     in LDS (32 KB); b^2,b^3 in-register.
//   - fp32 cross-quarter reduce in LDS (36 KB). LDS total 70 KB
//     (2 blocks/CU OK: 140 <= 160 KB).
//   - Per-term math identical to R2 -> absmax ~1.2e-10 (only fp32 add
//     order changes).
// Fragment layouts (m120/m89): A[m=lane&15][k=(lane>>4)*8+j],
//   B[k=(lane>>4)*8+j][n=lane&15], C col=lane&15, row=(lane>>4)*4+i.

typedef _Float16 v8h __attribute__((ext_vector_type(8)));
typedef float v4f __attribute__((ext_vector_type(4)));

#define DIM_B 2048
#define DIM_I 512
#define DIM_O 256

__global__ __launch_bounds__(512, 4) void l0conj_fused(
    const float* __restrict__ x,    // [2048][512]
    const float* __restrict__ w,    // [512][256]
    const float* __restrict__ qz,   // [512]
    float* __restrict__ out)        // [2048][256]
{
    const int t = threadIdx.x;
    const int lane = t & 63;
    const int wid = t >> 6;          // 0..7
    const int wm = wid & 1;          // m-tile within block
    const int qtr = wid >> 1;        // K quarter 0..3
    const int m16 = blockIdx.x * 2 + wm;    // 0..127
    const int npair = blockIdx.y;           // 0..7

    __shared__ float zS[DIM_I];              // 2 KB
    __shared__ _Float16 Bf[2][16][64][8];    // 32 KB: power-1 B frags, [n][ktile]
    __shared__ v4f red[2][3][2][3][64];      // 36 KB: [wm][qtr-1][n][pow][lane]

    const int r = lane & 15, q = lane >> 4;
    const float* xp = x + (size_t)(m16 * 16 + r) * DIM_I + qtr * 128 + q * 8;

    // ---- pre-issue the ENTIRE per-wave x tile (8x float4): HBM latency
    //      overlaps the whole preamble below.
    float4 xv0[4], xv1[4];
#pragma unroll
    for (int k = 0; k < 4; ++k) {
        xv0[k] = *(const float4*)(xp + k * 32);
        xv1[k] = *(const float4*)(xp + k * 32 + 4);
    }

    // ---- z gate (identical math; 512 threads = 1 element each)
    {
        float qv = qz[t];
        float sig = 1.0f / (1.0f + __expf(-qv));
        float z = fmaf(sig, 1.2f, -0.1f);
        zS[t] = fminf(fmaxf(z, 0.0f), 1.0f);
    }

    // ---- B power-1 fragments into LDS: 32 (n,ktile) builds, 4 per wave
    {
        const int c = lane & 15;
#pragma unroll
        for (int i = 0; i < 4; ++i) {
            const int idx = wid * 4 + i;     // 0..31
            const int nn = idx >> 4;         // 0..1
            const int kk = idx & 15;         // 0..15
            const float* wp = w + (size_t)(kk * 32 + q * 8) * DIM_O
                                + (npair * 2 + nn) * 16 + c;
            v8h b;
#pragma unroll
            for (int j = 0; j < 8; ++j) b[j] = (_Float16)wp[(size_t)j * DIM_O];
            *(v8h*)&Bf[nn][kk][lane][0] = b;
        }
    }
    __syncthreads();

    // ---- K-loop: 4 iters, 6 MFMA/iter, zero exposed global latency
    const float* zp0 = zS + qtr * 128 + q * 8;

    v4f s00 = {0.f, 0.f, 0.f, 0.f}, s01 = {0.f, 0.f, 0.f, 0.f};
    v4f s02 = {0.f, 0.f, 0.f, 0.f};
    v4f s10 = {0.f, 0.f, 0.f, 0.f}, s11 = {0.f, 0.f, 0.f, 0.f};
    v4f s12 = {0.f, 0.f, 0.f, 0.f};

#pragma unroll
    for (int k = 0; k < 4; ++k) {
        const float4 z0 = *(const float4*)(zp0 + k * 32);   // LDS broadcast
        const float4 z1 = *(const float4*)(zp0 + k * 32 + 4);
        const float4 x0 = xv0[k], x1 = xv1[k];
        v8h a;
        a[0] = (_Float16)fmaf(-x0.x, z0.x, 1.0f);
        a[1] = (_Float16)fmaf(-x0.y, z0.y, 1.0f);
        a[2] = (_Float16)fmaf(-x0.z, z0.z, 1.0f);
        a[3] = (_Float16)fmaf(-x0.w, z0.w, 1.0f);
        a[4] = (_Float16)fmaf(-x1.x, z1.x, 1.0f);
        a[5] = (_Float16)fmaf(-x1.y, z1.y, 1.0f);
        a[6] = (_Float16)fmaf(-x1.z, z1.z, 1.0f);
        a[7] = (_Float16)fmaf(-x1.w, z1.w, 1.0f);
        const v8h a2 = a * a;                 // v_pk_mul_f16
        const v8h a3 = a2 * a;
        const int kt = qtr * 4 + k;
        {
            const v8h b  = *(const v8h*)&Bf[0][kt][lane][0];
            const v8h b2 = b * b;
            const v8h b3 = b2 * b;
            s00 = __builtin_amdgcn_mfma_f32_16x16x32_f16(a,  b,  s00, 0, 0, 0);
            s01 = __builtin_amdgcn_mfma_f32_16x16x32_f16(a2, b2, s01, 0, 0, 0);
            s02 = __builtin_amdgcn_mfma_f32_16x16x32_f16(a3, b3, s02, 0, 0, 0);
        }
        {
            const v8h b  = *(const v8h*)&Bf[1][kt][lane][0];
            const v8h b2 = b * b;
            const v8h b3 = b2 * b;
            s10 = __builtin_amdgcn_mfma_f32_16x16x32_f16(a,  b,  s10, 0, 0, 0);
            s11 = __builtin_amdgcn_mfma_f32_16x16x32_f16(a2, b2, s11, 0, 0, 0);
            s12 = __builtin_amdgcn_mfma_f32_16x16x32_f16(a3, b3, s12, 0, 0, 0);
        }
    }

    // ---- cross-quarter reduce (fp32): quarters 1..3 store, quarter 0 sums
    if (qtr != 0) {
        red[wm][qtr - 1][0][0][lane] = s00;
        red[wm][qtr - 1][0][1][lane] = s01;
        red[wm][qtr - 1][0][2][lane] = s02;
        red[wm][qtr - 1][1][0][lane] = s10;
        red[wm][qtr - 1][1][1][lane] = s11;
        red[wm][qtr - 1][1][2][lane] = s12;
    }
    __syncthreads();
    if (qtr == 0) {
#pragma unroll
        for (int j = 0; j < 3; ++j) {
            s00 += red[wm][j][0][0][lane];
            s01 += red[wm][j][0][1][lane];
            s02 += red[wm][j][0][2][lane];
            s10 += red[wm][j][1][0][lane];
            s11 += red[wm][j][1][1][lane];
            s12 += red[wm][j][1][2][lane];
        }
        const int col = lane & 15;
        const int row4 = (lane >> 4) * 4;
        float* op0 = out + (size_t)(m16 * 16 + row4) * DIM_O + npair * 32 + col;
        float* op1 = op0 + 16;
#pragma unroll
        for (int i = 0; i < 4; ++i) {
            const float S0 = s00[i] + 0.5f * s01[i] + (1.0f / 3.0f) * s02[i];
            const float S1 = s10[i] + 0.5f * s11[i] + (1.0f / 3.0f) * s12[i];
            op0[(size_t)i * DIM_O] = __expf(-S0);
            op1[(size_t)i * DIM_O] = __expf(-S1);
        }
    }
}

extern "C" void kernel_launch(void* const* d_in, const int* in_sizes, int n_in,
                              void* d_out, int out_size, void* d_ws, size_t ws_size,
                              hipStream_t stream) {
    const float* x = (const float*)d_in[0];   // [2048, 512]
    const float* w = (const float*)d_in[1];   // [512, 256]
    const float* qz = (const float*)d_in[2];  // [512]
    float* out = (float*)d_out;               // [2048, 256]
    (void)d_ws; (void)ws_size;                // workspace intentionally unused

    l0conj_fused<<<dim3(64, 8), dim3(512), 0, stream>>>(x, w, qz, out);
}